// Round 3
// baseline (306.340 us; speedup 1.0000x reference)
//
#include <hip/hip_runtime.h>
#include <hip/hip_cooperative_groups.h>

namespace cg = cooperative_groups;

constexpr int Bn = 8;
constexpr int Ln = 4096;
constexpr int Dn = 768;
constexpr int CPB  = 64;             // chunks (blocks) per batch
constexpr int NBLK = Bn * CPB;       // 512 blocks = 2 per CU -> always co-resident
constexpr int RPB  = Ln / CPB;       // 64 rows per block

// ---------------------------------------------------------------------------
// Single cooperative kernel, 3 phases:
//  1: block (b,c) partial-colsums its 64 rows -> part[blockIdx][768]
//  2: blocks with c==0 fold the 64 partials of batch b, compute
//     m[b,d] = colsum[b,d] * ||colsum_b||^2 / (L^4 D^2)
//  3: block (b,c) re-reads its own 64 rows (L2/L3-hot) and writes
//     out = alpha[l] + (x_row . m_b) * x_row
// ---------------------------------------------------------------------------
__global__ void __launch_bounds__(256, 2)
k_all(const float* __restrict__ x, const float* __restrict__ alpha,
      float* __restrict__ out, float* __restrict__ part, float* __restrict__ m) {
    cg::grid_group grid = cg::this_grid();
    __shared__ float wsum[4];

    const int b = blockIdx.x >> 6;       // batch
    const int c = blockIdx.x & 63;       // chunk within batch
    const int t = threadIdx.x;           // 0..255
    const int wave = t >> 6, lane = t & 63;

    // ---- phase 1: partial column sums over this block's 64 rows ----
    {
        const float* xb = x + ((size_t)b * Ln + (size_t)c * RPB) * Dn;
        float s0 = 0.f, s1 = 0.f, s2 = 0.f;
        for (int l = 0; l < RPB; ++l) {
            const float* row = xb + (size_t)l * Dn;
            s0 += row[t];
            s1 += row[t + 256];
            s2 += row[t + 512];
        }
        float* pr = part + (size_t)blockIdx.x * Dn;
        pr[t]       = s0;
        pr[t + 256] = s1;
        pr[t + 512] = s2;
    }
    grid.sync();

    // ---- phase 2: fold partials -> pre-scaled m (one block per batch) ----
    if (c == 0) {
        const float* pb = part + (size_t)b * CPB * Dn;
        float s0 = 0.f, s1 = 0.f, s2 = 0.f;
        for (int k = 0; k < CPB; ++k) {
            const float* row = pb + (size_t)k * Dn;
            s0 += row[t];
            s1 += row[t + 256];
            s2 += row[t + 512];
        }
        float ssq = s0 * s0 + s1 * s1 + s2 * s2;
        #pragma unroll
        for (int off = 1; off < 64; off <<= 1) ssq += __shfl_xor(ssq, off);
        if (lane == 0) wsum[wave] = ssq;
        __syncthreads();
        float ss = wsum[0] + wsum[1] + wsum[2] + wsum[3];

        const float f1 = 1.0f / ((float)Ln * (float)Dn);
        float scale = ss * f1 * f1 / ((float)Ln * (float)Ln);
        m[b * Dn + t]       = s0 * scale;
        m[b * Dn + t + 256] = s1 * scale;
        m[b * Dn + t + 512] = s2 * scale;
    }
    grid.sync();

    // ---- phase 3: fused rowdot + epilogue over this block's own 64 rows ----
    {
        const float4* mr = (const float4*)(m + (size_t)b * Dn);
        float4 m0 = mr[lane], m1 = mr[lane + 64], m2 = mr[lane + 128];

        const int row0 = b * Ln + c * RPB;
        for (int r = wave; r < RPB; r += 4) {
            int row = row0 + r;
            int l   = c * RPB + r;
            const float4* xr = (const float4*)(x + (size_t)row * Dn);
            float4 x0 = xr[lane], x1 = xr[lane + 64], x2 = xr[lane + 128];

            float acc = x0.x * m0.x + x0.y * m0.y + x0.z * m0.z + x0.w * m0.w
                      + x1.x * m1.x + x1.y * m1.y + x1.z * m1.z + x1.w * m1.w
                      + x2.x * m2.x + x2.y * m2.y + x2.z * m2.z + x2.w * m2.w;
            #pragma unroll
            for (int off = 1; off < 64; off <<= 1) acc += __shfl_xor(acc, off);

            float a = alpha[l];
            float4* orow = (float4*)(out + (size_t)row * Dn);
            float4 o0 = {a + acc * x0.x, a + acc * x0.y, a + acc * x0.z, a + acc * x0.w};
            float4 o1 = {a + acc * x1.x, a + acc * x1.y, a + acc * x1.z, a + acc * x1.w};
            float4 o2 = {a + acc * x2.x, a + acc * x2.y, a + acc * x2.z, a + acc * x2.w};
            orow[lane]       = o0;
            orow[lane + 64]  = o1;
            orow[lane + 128] = o2;
        }
    }
}

// ---------------------------------------------------------------------------
extern "C" void kernel_launch(void* const* d_in, const int* in_sizes, int n_in,
                              void* d_out, int out_size, void* d_ws, size_t ws_size,
                              hipStream_t stream) {
    const float* x     = (const float*)d_in[0];   // [B, L, D]
    const float* alpha = (const float*)d_in[1];   // [L, 1]
    float* out = (float*)d_out;                   // [B, L, D]

    // ws layout: part[NBLK*D] | m[B*D]   (~1.6 MB)
    float* part = (float*)d_ws;
    float* m    = part + (size_t)NBLK * Dn;

    void* args[] = {(void*)&x, (void*)&alpha, (void*)&out, (void*)&part, (void*)&m};
    hipLaunchCooperativeKernel((void*)k_all, dim3(NBLK), dim3(256), args, 0, stream);
}

// Round 5
// 198.765 us; speedup vs baseline: 1.5412x; 1.5412x over previous
//
#include <hip/hip_runtime.h>

constexpr int Bn = 8;
constexpr int Ln = 4096;
constexpr int Dn = 768;
constexpr int NCH = 128;             // chunks per batch for partial colsum
constexpr int RPC = Ln / NCH;        // 32 rows per chunk

typedef float f4 __attribute__((ext_vector_type(4)));   // native vec4: works with nontemporal builtins

// ---------------------------------------------------------------------------
// K1: partial column sums (no atomics). grid = Bn*NCH = 1024 blocks x 192 thr
// (~12 waves/CU) -> enough outstanding float4 loads to be HBM-bound.
// part[chunk][d4] = sum over the chunk's 32 rows.
// ---------------------------------------------------------------------------
__global__ void k_colsum_part(const float* __restrict__ x, f4* __restrict__ part) {
    int b = blockIdx.x >> 7;             // / NCH
    int c = blockIdx.x & (NCH - 1);
    int t = threadIdx.x;                 // 0..191 (D/4 = 192)
    const f4* xb = (const f4*)(x + ((size_t)b * Ln + (size_t)c * RPC) * Dn);
    f4 s = {0.f, 0.f, 0.f, 0.f};
    #pragma unroll 4
    for (int l = 0; l < RPC; ++l) {
        s += xb[(size_t)l * (Dn / 4) + t];
    }
    part[(size_t)blockIdx.x * (Dn / 4) + t] = s;
}

// ---------------------------------------------------------------------------
// K2: fold partials -> colsum; m[b,d] = colsum[b,d] * ||colsum_b||^2/(L^4 D^2).
// (y_l = x_l.colsum/(LD); sum_y = ||colsum||^2/(LD); coef_l = y_l*sum_y/L^2 = x_l.m)
// grid = Bn x 256 threads; thread t owns d = t, t+256, t+512.
// ---------------------------------------------------------------------------
__global__ void k_scale(const float* __restrict__ part, float* __restrict__ m) {
    int b = blockIdx.x;
    int t = threadIdx.x;
    const float* pb = part + (size_t)b * NCH * Dn;
    float s0 = 0.f, s1 = 0.f, s2 = 0.f;
    for (int c = 0; c < NCH; ++c) {
        const float* row = pb + (size_t)c * Dn;
        s0 += row[t];
        s1 += row[t + 256];
        s2 += row[t + 512];
    }
    float ssq = s0 * s0 + s1 * s1 + s2 * s2;
    #pragma unroll
    for (int off = 1; off < 64; off <<= 1) ssq += __shfl_xor(ssq, off);
    __shared__ float wsum[4];
    int wave = t >> 6, lane = t & 63;
    if (lane == 0) wsum[wave] = ssq;
    __syncthreads();
    float ss = wsum[0] + wsum[1] + wsum[2] + wsum[3];

    const float f1 = 1.0f / ((float)Ln * (float)Dn);
    float scale = ss * f1 * f1 / ((float)Ln * (float)Ln);
    m[b * Dn + t]       = s0 * scale;
    m[b * Dn + t + 256] = s1 * scale;
    m[b * Dn + t + 512] = s2 * scale;
}

// ---------------------------------------------------------------------------
// K3: fused rowdot + epilogue. One wave per row, 4 waves/block, 2048 blocks
// (32 waves/CU). x held in registers for both dot and write-back.
// Nontemporal stores keep the write stream from evicting x in L2/L3.
// ---------------------------------------------------------------------------
__global__ void k_fused(const float* __restrict__ x, const float* __restrict__ m,
                        const float* __restrict__ alpha, float* __restrict__ out) {
    int wave = threadIdx.x >> 6;
    int lane = threadIdx.x & 63;
    int row  = blockIdx.x * 4 + wave;    // [0, B*L)
    int b    = row >> 12;
    int l    = row & (Ln - 1);

    const f4* xr = (const f4*)(x + (size_t)row * Dn);
    const f4* mr = (const f4*)(m + (size_t)b * Dn);

    f4 x0 = xr[lane], x1 = xr[lane + 64], x2 = xr[lane + 128];
    f4 m0 = mr[lane], m1 = mr[lane + 64], m2 = mr[lane + 128];

    f4 p = x0 * m0 + x1 * m1 + x2 * m2;
    float acc = p.x + p.y + p.z + p.w;
    #pragma unroll
    for (int off = 1; off < 64; off <<= 1) acc += __shfl_xor(acc, off);

    float a = alpha[l];
    f4* orow = (f4*)(out + (size_t)row * Dn);
    f4 o0 = a + acc * x0;
    f4 o1 = a + acc * x1;
    f4 o2 = a + acc * x2;
    __builtin_nontemporal_store(o0, &orow[lane]);
    __builtin_nontemporal_store(o1, &orow[lane + 64]);
    __builtin_nontemporal_store(o2, &orow[lane + 128]);
}

// ---------------------------------------------------------------------------
extern "C" void kernel_launch(void* const* d_in, const int* in_sizes, int n_in,
                              void* d_out, int out_size, void* d_ws, size_t ws_size,
                              hipStream_t stream) {
    const float* x     = (const float*)d_in[0];   // [B, L, D]
    const float* alpha = (const float*)d_in[1];   // [L, 1]
    float* out = (float*)d_out;                   // [B, L, D]

    // ws layout: part[Bn*NCH*Dn] (~3.1 MB) | m[Bn*Dn]
    float* part = (float*)d_ws;
    float* m    = part + (size_t)Bn * NCH * Dn;

    k_colsum_part<<<Bn * NCH, 192, 0, stream>>>(x, (f4*)part);
    k_scale<<<Bn, 256, 0, stream>>>(part, m);
    k_fused<<<(Bn * Ln) / 4, 256, 0, stream>>>(x, m, alpha, out);
}